// Round 18
// baseline (127.324 us; speedup 1.0000x reference)
//
#include <hip/hip_runtime.h>
#include <hip/hip_bf16.h>
#include <stdint.h>

typedef __attribute__((ext_vector_type(4))) float f32x4;
typedef __attribute__((ext_vector_type(16))) float f32x16;
typedef __attribute__((ext_vector_type(8))) short bf16x8;
typedef __attribute__((ext_vector_type(4))) unsigned int u32x4;
typedef __attribute__((ext_vector_type(2))) unsigned int u32x2;
typedef unsigned short u16;

#define GBL_AS1(p) ((const __attribute__((address_space(1))) void*)(p))
#define LDS_AS3(p) ((__attribute__((address_space(3))) void*)(p))

static __device__ __forceinline__ u16 f2bf(float f) {
  __hip_bfloat16 h = __float2bfloat16(f);
  union { __hip_bfloat16 h; u16 u; } c; c.h = h;
  return c.u;
}

// ---------------- weights fp32->bf16 cast + mask flags (~4us) ----------------
__global__ __launch_bounds__(256) void cast_weights(
    const float* __restrict__ wq_, const float* __restrict__ wk_,
    const float* __restrict__ wv_, const float* __restrict__ wo_,
    const int* __restrict__ mask,
    u16* __restrict__ WqB, u16* __restrict__ WkB,
    u16* __restrict__ WvB, u16* __restrict__ WoB,
    int* __restrict__ flags) {
  if (blockIdx.x == 0 && threadIdx.x < 64) {
    int bb = threadIdx.x >> 4, kt = threadIdx.x & 15;
    int anyz = 0;
    for (int s = 0; s < 64; ++s) anyz |= (mask[bb * 1024 + kt * 64 + s] == 0);
    flags[threadIdx.x] = anyz;
  }
  int idx = blockIdx.x * 256 + threadIdx.x;
#pragma unroll
  for (int j = 0; j < 4; ++j) {
    int i = idx + j * 262144;
    int w = i >> 18, off = i & 262143;
    const float* src = (w == 0) ? wq_ : (w == 1) ? wk_ : (w == 2) ? wv_ : wo_;
    u16* dst = (w == 0) ? WqB : (w == 1) ? WkB : (w == 2) ? WvB : WoB;
    float4 v = reinterpret_cast<const float4*>(src)[off];
    ushort4 ov;
    ov.x = f2bf(v.x); ov.y = f2bf(v.y); ov.z = f2bf(v.z); ov.w = f2bf(v.w);
    reinterpret_cast<ushort4*>(dst)[off] = ov;
  }
}

// ---------------- 128x128 NT-GEMM core (m97 structure), kept for out_gemm ----------------
static __device__ __forceinline__ void gemm_core(const u16* __restrict__ Atile,
                                                 const u16* __restrict__ Btile,
                                                 u16* lds_a, u16* lds_b,
                                                 f32x4 acc[4][4]) {
  const int tid = threadIdx.x;
  const int lane = tid & 63;
  const int wv = tid >> 6;
  const int wm = wv >> 1, wn = wv & 1;
  const int fr = lane & 15, fq = lane >> 4;
  for (int kt = 0; kt < 32; ++kt) {
#pragma unroll
    for (int i = 0; i < 2; ++i) {
      const int cb = (wv * 2 + i) * 64;
      const int c = cb + lane;
      const int row = c >> 2;
      const int off = (c & 3) * 8;
      __builtin_amdgcn_global_load_lds(GBL_AS1(Atile + (size_t)row * 1024 + kt * 32 + off),
                                       LDS_AS3(lds_a + cb * 8), 16, 0, 0);
      __builtin_amdgcn_global_load_lds(GBL_AS1(Btile + (size_t)row * 1024 + kt * 32 + off),
                                       LDS_AS3(lds_b + cb * 8), 16, 0, 0);
    }
    __syncthreads();
    bf16x8 af[4], bfv[4];
#pragma unroll
    for (int mi = 0; mi < 4; ++mi)
      af[mi] = *(const bf16x8*)&lds_a[(wm * 64 + mi * 16 + fr) * 32 + fq * 8];
#pragma unroll
    for (int ni = 0; ni < 4; ++ni)
      bfv[ni] = *(const bf16x8*)&lds_b[(wn * 64 + ni * 16 + fr) * 32 + fq * 8];
#pragma unroll
    for (int mi = 0; mi < 4; ++mi)
#pragma unroll
      for (int ni = 0; ni < 4; ++ni)
        acc[mi][ni] = __builtin_amdgcn_mfma_f32_16x16x32_bf16(af[mi], bfv[ni], acc[mi][ni], 0, 0, 0);
    __syncthreads();
  }
}

// ---------------- MERGED QKV: one block computes Q, K, V for (mt, ntl) ----------------
// Rationale: 17 rounds showed qkv is latency-window-bound (~900cy/window vs
// ~175 busy). Merging triples busy work per window (48 MFMA/wave) and pays the
// window cost ONCE for 3 outputs; grid 256 = exactly 1 block/CU (one pass, no
// convoying). VGPR ~290 is fine under launch_bounds(256,1) — occupancy beyond
// 1 wave/SIMD is unusable at this grid anyway. A-tiles (aspect+opinion) staged
// fp32->bf16 in-register (r17-validated layout); weights via global_load_lds
// (r16-validated). All acc/epilogue indexing static (named acc0/1/2).
__global__ __launch_bounds__(256, 1) void qkv_gemm(
    const float* __restrict__ aspect32, const float* __restrict__ opinion32,
    const u16* __restrict__ Wq, const u16* __restrict__ Wk, const u16* __restrict__ Wv,
    const float* __restrict__ bq, const float* __restrict__ bk, const float* __restrict__ bv,
    u16* __restrict__ q_ws, u16* __restrict__ k_ws, u16* __restrict__ vt_ws) {
  __shared__ __align__(16) u16 asp_lds[128 * 32];
  __shared__ __align__(16) u16 opi_lds[128 * 32];
  __shared__ __align__(16) u16 bq_lds[128 * 32];
  __shared__ __align__(16) u16 bk_lds[128 * 32];
  __shared__ __align__(16) u16 bv_lds[128 * 32];
  const int mt = blockIdx.x, ntl = blockIdx.y;
  const float* Aa = aspect32 + (size_t)mt * 128 * 1024;
  const float* Ao = opinion32 + (size_t)mt * 128 * 1024;
  const u16* Bq = Wq + (size_t)ntl * 128 * 1024;
  const u16* Bk = Wk + (size_t)ntl * 128 * 1024;
  const u16* Bv = Wv + (size_t)ntl * 128 * 1024;

  const int tid = threadIdx.x, lane = tid & 63, wv = tid >> 6;
  const int wm = wv >> 1, wn = wv & 1;
  const int fr = lane & 15, fq = lane >> 4;

  f32x4 acc0[4][4], acc1[4][4], acc2[4][4];
#pragma unroll
  for (int i = 0; i < 4; ++i)
#pragma unroll
    for (int j = 0; j < 4; ++j) {
      acc0[i][j] = (f32x4){0.f, 0.f, 0.f, 0.f};
      acc1[i][j] = (f32x4){0.f, 0.f, 0.f, 0.f};
      acc2[i][j] = (f32x4){0.f, 0.f, 0.f, 0.f};
    }

  for (int kt = 0; kt < 32; ++kt) {
    // A fp32 loads (both matrices), issued first so latency overlaps B staging
    float4 a0[2], a1[2], o0[2], o1[2];
#pragma unroll
    for (int i = 0; i < 2; ++i) {
      const int c = (wv * 2 + i) * 64 + lane;
      const int row = c >> 2;
      const int off = (c & 3) * 8;
      const float* sa = Aa + (size_t)row * 1024 + kt * 32 + off;
      a0[i] = *(const float4*)sa;
      a1[i] = *(const float4*)(sa + 4);
      const float* so = Ao + (size_t)row * 1024 + kt * 32 + off;
      o0[i] = *(const float4*)so;
      o1[i] = *(const float4*)(so + 4);
    }
    // B: 3 weight panels via global_load_lds
#pragma unroll
    for (int i = 0; i < 2; ++i) {
      const int cb = (wv * 2 + i) * 64;
      const int c = cb + lane;
      const int row = c >> 2;
      const int off = (c & 3) * 8;
      __builtin_amdgcn_global_load_lds(GBL_AS1(Bq + (size_t)row * 1024 + kt * 32 + off),
                                       LDS_AS3(bq_lds + cb * 8), 16, 0, 0);
      __builtin_amdgcn_global_load_lds(GBL_AS1(Bk + (size_t)row * 1024 + kt * 32 + off),
                                       LDS_AS3(bk_lds + cb * 8), 16, 0, 0);
      __builtin_amdgcn_global_load_lds(GBL_AS1(Bv + (size_t)row * 1024 + kt * 32 + off),
                                       LDS_AS3(bv_lds + cb * 8), 16, 0, 0);
    }
    // cvt + ds_write both A tiles (byte-identical LDS layout to bf16 path)
#pragma unroll
    for (int i = 0; i < 2; ++i) {
      const int c = (wv * 2 + i) * 64 + lane;
      unsigned int w0, w1, w2, w3;
      asm("v_cvt_pk_bf16_f32 %0, %1, %2" : "=v"(w0) : "v"(a0[i].x), "v"(a0[i].y));
      asm("v_cvt_pk_bf16_f32 %0, %1, %2" : "=v"(w1) : "v"(a0[i].z), "v"(a0[i].w));
      asm("v_cvt_pk_bf16_f32 %0, %1, %2" : "=v"(w2) : "v"(a1[i].x), "v"(a1[i].y));
      asm("v_cvt_pk_bf16_f32 %0, %1, %2" : "=v"(w3) : "v"(a1[i].z), "v"(a1[i].w));
      *(u32x4*)&asp_lds[c * 8] = (u32x4){w0, w1, w2, w3};
      asm("v_cvt_pk_bf16_f32 %0, %1, %2" : "=v"(w0) : "v"(o0[i].x), "v"(o0[i].y));
      asm("v_cvt_pk_bf16_f32 %0, %1, %2" : "=v"(w1) : "v"(o0[i].z), "v"(o0[i].w));
      asm("v_cvt_pk_bf16_f32 %0, %1, %2" : "=v"(w2) : "v"(o1[i].x), "v"(o1[i].y));
      asm("v_cvt_pk_bf16_f32 %0, %1, %2" : "=v"(w3) : "v"(o1[i].z), "v"(o1[i].w));
      *(u32x4*)&opi_lds[c * 8] = (u32x4){w0, w1, w2, w3};
    }
    __syncthreads();

    bf16x8 afa[4], afo[4], bfv[4];
#pragma unroll
    for (int mi = 0; mi < 4; ++mi) {
      const int r = (wm * 64 + mi * 16 + fr) * 32 + fq * 8;
      afa[mi] = *(const bf16x8*)&asp_lds[r];
      afo[mi] = *(const bf16x8*)&opi_lds[r];
    }
    // Q = aspect x Wq
#pragma unroll
    for (int ni = 0; ni < 4; ++ni)
      bfv[ni] = *(const bf16x8*)&bq_lds[(wn * 64 + ni * 16 + fr) * 32 + fq * 8];
#pragma unroll
    for (int mi = 0; mi < 4; ++mi)
#pragma unroll
      for (int ni = 0; ni < 4; ++ni)
        acc0[mi][ni] = __builtin_amdgcn_mfma_f32_16x16x32_bf16(afa[mi], bfv[ni], acc0[mi][ni], 0, 0, 0);
    // K = opinion x Wk
#pragma unroll
    for (int ni = 0; ni < 4; ++ni)
      bfv[ni] = *(const bf16x8*)&bk_lds[(wn * 64 + ni * 16 + fr) * 32 + fq * 8];
#pragma unroll
    for (int mi = 0; mi < 4; ++mi)
#pragma unroll
      for (int ni = 0; ni < 4; ++ni)
        acc1[mi][ni] = __builtin_amdgcn_mfma_f32_16x16x32_bf16(afo[mi], bfv[ni], acc1[mi][ni], 0, 0, 0);
    // V = opinion x Wv
#pragma unroll
    for (int ni = 0; ni < 4; ++ni)
      bfv[ni] = *(const bf16x8*)&bv_lds[(wn * 64 + ni * 16 + fr) * 32 + fq * 8];
#pragma unroll
    for (int mi = 0; mi < 4; ++mi)
#pragma unroll
      for (int ni = 0; ni < 4; ++ni)
        acc2[mi][ni] = __builtin_amdgcn_mfma_f32_16x16x32_bf16(afo[mi], bfv[ni], acc2[mi][ni], 0, 0, 0);
    __syncthreads();
  }

  // ---- epilogue: Q (pre-scaled), K, V^T ----
#pragma unroll
  for (int mi = 0; mi < 4; ++mi)
#pragma unroll
    for (int ni = 0; ni < 4; ++ni)
#pragma unroll
      for (int r = 0; r < 4; ++r) {
        int m = mt * 128 + wm * 64 + mi * 16 + fq * 4 + r;
        int nl = ntl * 128 + wn * 64 + ni * 16 + fr;
        int b = m >> 10, s = m & 1023, h = nl >> 6, d = nl & 63;
        size_t qkoff = (((size_t)(b * 16 + h)) * 1024 + s) * 64 + d;
        q_ws[qkoff] = f2bf((acc0[mi][ni][r] + bq[nl]) * 0.18033688f);
        k_ws[qkoff] = f2bf(acc1[mi][ni][r] + bk[nl]);
        vt_ws[(((size_t)(b * 16 + h)) * 64 + d) * 1024 + s] = f2bf(acc2[mi][ni][r] + bv[nl]);
      }
}

// ---------------- flash attention, swapped-QK^T 32x32, KVBLK=64 (byte-identical r16) ----------------
__global__ __launch_bounds__(256, 4) void attn_kernel(
    const u16* __restrict__ q_ws, const u16* __restrict__ k_ws,
    const u16* __restrict__ vt_ws, const int* __restrict__ mask,
    const int* __restrict__ flags, u16* __restrict__ ctx_ws) {
  __shared__ __align__(16) u16 k_lds[2][64 * 64];   // K [64 keys][64 d], chunk-swizzled
  __shared__ __align__(16) u16 vt_lds[2][64 * 64];  // V^T [64 d][64 keys], chunk-swizzled
  __shared__ __align__(16) float scl_lds[4][32];
  const int bid = blockIdx.x;
  const int bh = bid & 63, qt = bid >> 6;
  const int b = bh >> 4, h = bh & 15;
  const int tid = threadIdx.x, lane = tid & 63, wv = tid >> 6;
  const int l31 = lane & 31, hi = lane >> 5;
  const u16* qbase = q_ws + (size_t)bh * 65536 + (size_t)qt * 8192;
  const u16* kbase = k_ws + (size_t)bh * 65536;
  const u16* vtbase = vt_ws + (size_t)bh * 65536;

#define STAGE_KV(kt_, buf_) do { \
    _Pragma("unroll") \
    for (int i_ = 0; i_ < 2; ++i_) { \
      int cb_ = (wv * 2 + i_) * 64; \
      int c_ = cb_ + lane; \
      int r_ = c_ >> 3; \
      int sc_ = ((c_ & 7) ^ (r_ & 7)) * 8; \
      __builtin_amdgcn_global_load_lds(GBL_AS1(kbase + (size_t)((kt_) * 64 + r_) * 64 + sc_), \
                                       LDS_AS3(&k_lds[buf_][cb_ * 8]), 16, 0, 0); \
      __builtin_amdgcn_global_load_lds(GBL_AS1(vtbase + (size_t)r_ * 1024 + (kt_) * 64 + sc_), \
                                       LDS_AS3(&vt_lds[buf_][cb_ * 8]), 16, 0, 0); \
    } \
  } while (0)

  // ---- prologue: stage Q [128][64] into k_lds area (scratch), read B-frags ----
  {
    u16* qstage = &k_lds[0][0];
#pragma unroll
    for (int i_ = 0; i_ < 4; ++i_) {
      int cb_ = (wv * 4 + i_) * 64;
      int c_ = cb_ + lane;
      int r_ = c_ >> 3;
      int sc_ = ((c_ & 7) ^ (r_ & 7)) * 8;
      __builtin_amdgcn_global_load_lds(GBL_AS1(qbase + (size_t)r_ * 64 + sc_),
                                       LDS_AS3(qstage + cb_ * 8), 16, 0, 0);
    }
  }
  __syncthreads();
  bf16x8 qf[4];
  {
    int rq = wv * 32 + l31;
    const u16* qr = &k_lds[0][0] + rq * 64;
    int rx = rq & 7;
#pragma unroll
    for (int ds = 0; ds < 4; ++ds)
      qf[ds] = *(const bf16x8*)&qr[((ds * 2 + hi) ^ rx) * 8];
  }
  __syncthreads();
  STAGE_KV(0, 0);
  __syncthreads();

  f32x16 ctx0, ctx1;
#pragma unroll
  for (int z = 0; z < 16; ++z) { ctx0[z] = 0.f; ctx1[z] = 0.f; }
  float psum_half = 0.f;  // this half's running row-sum (disjoint key slots)

  for (int kt = 0; kt < 16; ++kt) {
    const int cur = kt & 1;
    if (kt < 15) STAGE_KV(kt + 1, cur ^ 1);

    // ---- QK^T swapped: D[key][q], lane q = l31, regs = keys (Q pre-scaled) ----
    f32x16 sc[2];
#pragma unroll
    for (int kb = 0; kb < 2; ++kb) {
      f32x16 a;
#pragma unroll
      for (int z = 0; z < 16; ++z) a[z] = 0.f;
      int r = kb * 32 + l31;
      const u16* kr = &k_lds[cur][r * 64];
      int rx = r & 7;
#pragma unroll
      for (int ds = 0; ds < 4; ++ds) {
        bf16x8 kf = *(const bf16x8*)&kr[((ds * 2 + hi) ^ rx) * 8];
        a = __builtin_amdgcn_mfma_f32_32x32x16_bf16(kf, qf[ds], a, 0, 0, 0);
      }
      sc[kb] = a;
    }

    // ---- mask slow path (uniform branch; all-ones input skips entirely) ----
    if (flags[b * 16 + kt]) {
#pragma unroll
      for (int kb = 0; kb < 2; ++kb)
#pragma unroll
        for (int r2 = 0; r2 < 16; ++r2) {
          int key = kb * 32 + (r2 & 3) + 8 * (r2 >> 2) + 4 * hi;
          if (mask[b * 1024 + kt * 64 + key] == 0) sc[kb][r2] = -30000.0f;
        }
    }

    // ---- exp2 (fixed reference) + local row-sum ----
#pragma unroll
    for (int kb = 0; kb < 2; ++kb)
#pragma unroll
      for (int r2 = 0; r2 < 16; ++r2) {
        float p = __builtin_exp2f(sc[kb][r2]);
        sc[kb][r2] = p;
        psum_half += p;
      }

    // ---- P -> bf16 A-frags via cvt_pk + permlane32_swap, then PV ----
#pragma unroll
    for (int kb = 0; kb < 2; ++kb) {
      unsigned int w[8];
#pragma unroll
      for (int j = 0; j < 8; ++j) {
        unsigned int t;
        asm("v_cvt_pk_bf16_f32 %0, %1, %2" : "=v"(t) : "v"(sc[kb][2 * j]), "v"(sc[kb][2 * j + 1]));
        w[j] = t;
      }
      u32x2 a0 = __builtin_amdgcn_permlane32_swap(w[0], w[2], false, false);
      u32x2 a1 = __builtin_amdgcn_permlane32_swap(w[1], w[3], false, false);
      u32x2 a2 = __builtin_amdgcn_permlane32_swap(w[4], w[6], false, false);
      u32x2 a3 = __builtin_amdgcn_permlane32_swap(w[5], w[7], false, false);
      union { u32x4 u; bf16x8 b; } P0, P1;
      P0.u = (u32x4){ a0[0], a1[0], a0[1], a1[1] };
      P1.u = (u32x4){ a2[0], a3[0], a2[1], a3[1] };
#pragma unroll
      for (int db = 0; db < 2; ++db) {
        int rv = db * 32 + l31;
        const u16* vr = &vt_lds[cur][rv * 64];
        int rvx = rv & 7;
        bf16x8 v0 = *(const bf16x8*)&vr[((kb * 4 + hi) ^ rvx) * 8];
        bf16x8 v1 = *(const bf16x8*)&vr[((kb * 4 + 2 + hi) ^ rvx) * 8];
        if (db == 0) {
          ctx0 = __builtin_amdgcn_mfma_f32_32x32x16_bf16(P0.b, v0, ctx0, 0, 0, 0);
          ctx0 = __builtin_amdgcn_mfma_f32_32x32x16_bf16(P1.b, v1, ctx0, 0, 0, 0);
        } else {
          ctx1 = __builtin_amdgcn_mfma_f32_32x32x16_bf16(P0.b, v0, ctx1, 0, 0, 0);
          ctx1 = __builtin_amdgcn_mfma_f32_32x32x16_bf16(P1.b, v1, ctx1, 0, 0, 0);
        }
      }
    }
    __syncthreads();
  }

  // ---- epilogue: combine half-sums, normalize, store ctx [b][s][h*64+d] ----
  float lrow = psum_half + __shfl_xor(psum_half, 32);
  float inv = (lrow > 0.f) ? 1.0f / lrow : 0.f;
  if (hi == 0) scl_lds[wv][l31] = inv;
  asm volatile("s_waitcnt lgkmcnt(0)" ::: "memory");
  const int sbase = qt * 128 + wv * 32;
#pragma unroll
  for (int g = 0; g < 4; ++g) {
    float4 s4 = *(const float4*)&scl_lds[wv][g * 8 + hi * 4];
    const float* sp = (const float*)&s4;
#pragma unroll
    for (int i2 = 0; i2 < 4; ++i2) {
      int s = sbase + g * 8 + hi * 4 + i2;
      size_t rowoff = ((size_t)(b * 1024 + s)) * 1024 + h * 64;
      ctx_ws[rowoff + l31]      = f2bf(ctx0[g * 4 + i2] * sp[i2]);
      ctx_ws[rowoff + 32 + l31] = f2bf(ctx1[g * 4 + i2] * sp[i2]);
    }
  }
#undef STAGE_KV
}

// ---------------- output projection: out = ctx @ Wo^T + bo (byte-identical r16) ----------------
__global__ __launch_bounds__(256) void out_gemm(const u16* __restrict__ ctxB,
                                                const u16* __restrict__ Wo,
                                                const float* __restrict__ bo,
                                                float* __restrict__ out) {
  __shared__ __align__(16) u16 lds_a[128 * 32];
  __shared__ __align__(16) u16 lds_b[128 * 32];
  const int mt = blockIdx.x, nt = blockIdx.y;
  f32x4 acc[4][4];
#pragma unroll
  for (int i = 0; i < 4; ++i)
#pragma unroll
    for (int j = 0; j < 4; ++j) acc[i][j] = (f32x4){0.f, 0.f, 0.f, 0.f};
  gemm_core(ctxB + (size_t)mt * 128 * 1024, Wo + (size_t)nt * 128 * 1024, lds_a, lds_b, acc);
  const int lane = threadIdx.x & 63, wvi = threadIdx.x >> 6;
  const int wm = wvi >> 1, wn = wvi & 1, fr = lane & 15, fq = lane >> 4;
#pragma unroll
  for (int mi = 0; mi < 4; ++mi)
#pragma unroll
    for (int ni = 0; ni < 4; ++ni)
#pragma unroll
      for (int r = 0; r < 4; ++r) {
        int m = mt * 128 + wm * 64 + mi * 16 + fq * 4 + r;
        int n = nt * 128 + wn * 64 + ni * 16 + fr;
        out[(size_t)m * 1024 + n] = acc[mi][ni][r] + bo[n];
      }
}

extern "C" void kernel_launch(void* const* d_in, const int* in_sizes, int n_in,
                              void* d_out, int out_size, void* d_ws, size_t ws_size,
                              hipStream_t stream) {
  const float* aspect = (const float*)d_in[0];
  const float* opinion = (const float*)d_in[1];
  const int* mask = (const int*)d_in[2];
  const float* Wq = (const float*)d_in[3];
  const float* bq = (const float*)d_in[4];
  const float* Wk = (const float*)d_in[5];
  const float* bk = (const float*)d_in[6];
  const float* Wv = (const float*)d_in[7];
  const float* bv = (const float*)d_in[8];
  const float* Wo = (const float*)d_in[9];
  const float* bo = (const float*)d_in[10];
  // Wbil/bbil unused: span bias is constant along the softmax axis -> cancels.
  float* out = (float*)d_out;
  char* ws = (char*)d_ws;

  const size_t MB = 1u << 20;
  u16* WqB   = (u16*)(ws + 16 * MB);
  u16* WkB   = (u16*)(ws + 18 * MB);
  u16* WvB   = (u16*)(ws + 20 * MB);
  u16* WoB   = (u16*)(ws + 22 * MB);
  u16* q_ws  = (u16*)(ws + 24 * MB);  // [b][h][s][d], pre-scaled by 0.125*log2e
  u16* k_ws  = (u16*)(ws + 32 * MB);  // [b][h][s][d]
  u16* vt_ws = (u16*)(ws + 40 * MB);  // [b][h][d][s]
  u16* ctx_ws= (u16*)(ws + 48 * MB);  // [b][s][h*64+d]
  // mask flags in the tail of d_out: written by cast_weights, read by attn,
  // then overwritten by out_gemm (stream-ordered; deterministic every call).
  int* flags = (int*)(out + out_size - 64);

  cast_weights<<<1024, 256, 0, stream>>>(Wq, Wk, Wv, Wo, mask,
                                         WqB, WkB, WvB, WoB, flags);
  qkv_gemm<<<dim3(32, 8), 256, 0, stream>>>(aspect, opinion, WqB, WkB, WvB,
                                            bq, bk, bv, q_ws, k_ws, vt_ws);
  attn_kernel<<<512, 256, 0, stream>>>(q_ws, k_ws, vt_ws, mask, flags, ctx_ws);
  out_gemm<<<dim3(32, 8), 256, 0, stream>>>(ctx_ws, WoB, bo, out);
}

// Round 19
// 109.441 us; speedup vs baseline: 1.1634x; 1.1634x over previous
//
#include <hip/hip_runtime.h>
#include <hip/hip_bf16.h>
#include <stdint.h>

typedef __attribute__((ext_vector_type(4))) float f32x4;
typedef __attribute__((ext_vector_type(16))) float f32x16;
typedef __attribute__((ext_vector_type(8))) short bf16x8;
typedef __attribute__((ext_vector_type(4))) unsigned int u32x4;
typedef __attribute__((ext_vector_type(2))) unsigned int u32x2;
typedef unsigned short u16;

#define GBL_AS1(p) ((const __attribute__((address_space(1))) void*)(p))
#define LDS_AS3(p) ((__attribute__((address_space(3))) void*)(p))

static __device__ __forceinline__ u16 f2bf(float f) {
  __hip_bfloat16 h = __float2bfloat16(f);
  union { __hip_bfloat16 h; u16 u; } c; c.h = h;
  return c.u;
}

// ---------------- fused fp32->bf16 casts + mask flags (1 launch) ----------------
__global__ __launch_bounds__(256) void fused_cast(
    const float* __restrict__ a, const float* __restrict__ o,
    const float* __restrict__ wq_, const float* __restrict__ wk_,
    const float* __restrict__ wv_, const float* __restrict__ wo_,
    const int* __restrict__ mask,
    u16* __restrict__ aB, u16* __restrict__ oB,
    u16* __restrict__ WqB, u16* __restrict__ WkB,
    u16* __restrict__ WvB, u16* __restrict__ WoB,
    int* __restrict__ flags) {
  if (blockIdx.x == 0 && threadIdx.x < 64) {
    int bb = threadIdx.x >> 4, kt = threadIdx.x & 15;
    int anyz = 0;
    for (int s = 0; s < 64; ++s) anyz |= (mask[bb * 1024 + kt * 64 + s] == 0);
    flags[threadIdx.x] = anyz;
  }
  int idx = blockIdx.x * 256 + threadIdx.x;
#pragma unroll
  for (int j = 0; j < 4; ++j) {
    int i = idx + j * 786432;
    const float* src; u16* dst; int off;
    if (i < 1048576) { src = a; dst = aB; off = i; }
    else if (i < 2097152) { src = o; dst = oB; off = i - 1048576; }
    else {
      int w = (i - 2097152) >> 18; off = (i - 2097152) & 262143;
      src = (w == 0) ? wq_ : (w == 1) ? wk_ : (w == 2) ? wv_ : wo_;
      dst = (w == 0) ? WqB : (w == 1) ? WkB : (w == 2) ? WvB : WoB;
    }
    float4 v = reinterpret_cast<const float4*>(src)[off];
    ushort4 ov;
    ov.x = f2bf(v.x); ov.y = f2bf(v.y); ov.z = f2bf(v.z); ov.w = f2bf(v.w);
    reinterpret_cast<ushort4*>(dst)[off] = ov;
  }
}

// ---------------- 128x128 NT-GEMM core (m97 structure): BK=32, single buffer ----------------
// Empirical optimum for this K=1024 shape across 9 measured structural axes:
// 2-dbuf(61.9), 3-deep vmcnt(53.5), BK=64 swizzled(47.4), stagger(51.6),
// 64x128 breadth(65.2), branchy epilogue(52), reg-staged A(52-64),
// merged-QKV(72-79) all lost to this 43.6us structure. Do not perturb.
static __device__ __forceinline__ void gemm_core(const u16* __restrict__ Atile,
                                                 const u16* __restrict__ Btile,
                                                 u16* lds_a, u16* lds_b,
                                                 f32x4 acc[4][4]) {
  const int tid = threadIdx.x;
  const int lane = tid & 63;
  const int wv = tid >> 6;
  const int wm = wv >> 1, wn = wv & 1;
  const int fr = lane & 15, fq = lane >> 4;
  for (int kt = 0; kt < 32; ++kt) {
#pragma unroll
    for (int i = 0; i < 2; ++i) {
      const int cb = (wv * 2 + i) * 64;
      const int c = cb + lane;
      const int row = c >> 2;
      const int off = (c & 3) * 8;
      __builtin_amdgcn_global_load_lds(GBL_AS1(Atile + (size_t)row * 1024 + kt * 32 + off),
                                       LDS_AS3(lds_a + cb * 8), 16, 0, 0);
      __builtin_amdgcn_global_load_lds(GBL_AS1(Btile + (size_t)row * 1024 + kt * 32 + off),
                                       LDS_AS3(lds_b + cb * 8), 16, 0, 0);
    }
    __syncthreads();
    bf16x8 af[4], bfv[4];
#pragma unroll
    for (int mi = 0; mi < 4; ++mi)
      af[mi] = *(const bf16x8*)&lds_a[(wm * 64 + mi * 16 + fr) * 32 + fq * 8];
#pragma unroll
    for (int ni = 0; ni < 4; ++ni)
      bfv[ni] = *(const bf16x8*)&lds_b[(wn * 64 + ni * 16 + fr) * 32 + fq * 8];
#pragma unroll
    for (int mi = 0; mi < 4; ++mi)
#pragma unroll
      for (int ni = 0; ni < 4; ++ni)
        acc[mi][ni] = __builtin_amdgcn_mfma_f32_16x16x32_bf16(af[mi], bfv[ni], acc[mi][ni], 0, 0, 0);
    __syncthreads();
  }
}

// ---------------- fused QKV projection ----------------
__global__ __launch_bounds__(256) void qkv_gemm(
    const u16* __restrict__ aB, const u16* __restrict__ oB,
    const u16* __restrict__ Wq, const u16* __restrict__ Wk, const u16* __restrict__ Wv,
    const float* __restrict__ bq, const float* __restrict__ bk, const float* __restrict__ bv,
    u16* __restrict__ q_ws, u16* __restrict__ k_ws, u16* __restrict__ vt_ws) {
  __shared__ __align__(16) u16 lds_a[128 * 32];
  __shared__ __align__(16) u16 lds_b[128 * 32];
  const int mt = blockIdx.x;
  const int nt = blockIdx.y;
  const int w = nt >> 3, ntl = nt & 7;
  const u16* A = (w == 0) ? aB : oB;
  const u16* W = (w == 0) ? Wq : (w == 1) ? Wk : Wv;
  const float* bias = (w == 0) ? bq : (w == 1) ? bk : bv;
  f32x4 acc[4][4];
#pragma unroll
  for (int i = 0; i < 4; ++i)
#pragma unroll
    for (int j = 0; j < 4; ++j) acc[i][j] = (f32x4){0.f, 0.f, 0.f, 0.f};
  gemm_core(A + (size_t)mt * 128 * 1024, W + (size_t)ntl * 128 * 1024, lds_a, lds_b, acc);
  const int lane = threadIdx.x & 63, wvi = threadIdx.x >> 6;
  const int wm = wvi >> 1, wn = wvi & 1, fr = lane & 15, fq = lane >> 4;
  u16* dst01 = (w == 0) ? q_ws : k_ws;
  const float qscl = (w == 0) ? 0.18033688f : 1.0f;  // 0.125 * log2(e) folded into Q
#pragma unroll
  for (int mi = 0; mi < 4; ++mi)
#pragma unroll
    for (int ni = 0; ni < 4; ++ni)
#pragma unroll
      for (int r = 0; r < 4; ++r) {
        int m = mt * 128 + wm * 64 + mi * 16 + fq * 4 + r;
        int nl = ntl * 128 + wn * 64 + ni * 16 + fr;
        float v = (acc[mi][ni][r] + bias[nl]) * qscl;
        int b = m >> 10, s = m & 1023, h = nl >> 6, d = nl & 63;
        u16 u = f2bf(v);
        if (w < 2) dst01[(((size_t)(b * 16 + h)) * 1024 + s) * 64 + d] = u;
        else       vt_ws[(((size_t)(b * 16 + h)) * 64 + d) * 1024 + s] = u;
      }
}

// ---------------- flash attention, swapped-QK^T 32x32, KVBLK=64 ----------------
// Fixed-reference softmax (exact by shift-invariance), per-half deferred sum,
// permlane32_swap for the P cross-half exchange. V LDS-staged via
// global_load_lds (V-direct gather measured -22us in r15).
__global__ __launch_bounds__(256, 4) void attn_kernel(
    const u16* __restrict__ q_ws, const u16* __restrict__ k_ws,
    const u16* __restrict__ vt_ws, const int* __restrict__ mask,
    const int* __restrict__ flags, u16* __restrict__ ctx_ws) {
  __shared__ __align__(16) u16 k_lds[2][64 * 64];   // K [64 keys][64 d], chunk-swizzled
  __shared__ __align__(16) u16 vt_lds[2][64 * 64];  // V^T [64 d][64 keys], chunk-swizzled
  __shared__ __align__(16) float scl_lds[4][32];
  const int bid = blockIdx.x;
  const int bh = bid & 63, qt = bid >> 6;
  const int b = bh >> 4, h = bh & 15;
  const int tid = threadIdx.x, lane = tid & 63, wv = tid >> 6;
  const int l31 = lane & 31, hi = lane >> 5;
  const u16* qbase = q_ws + (size_t)bh * 65536 + (size_t)qt * 8192;
  const u16* kbase = k_ws + (size_t)bh * 65536;
  const u16* vtbase = vt_ws + (size_t)bh * 65536;

#define STAGE_KV(kt_, buf_) do { \
    _Pragma("unroll") \
    for (int i_ = 0; i_ < 2; ++i_) { \
      int cb_ = (wv * 2 + i_) * 64; \
      int c_ = cb_ + lane; \
      int r_ = c_ >> 3; \
      int sc_ = ((c_ & 7) ^ (r_ & 7)) * 8; \
      __builtin_amdgcn_global_load_lds(GBL_AS1(kbase + (size_t)((kt_) * 64 + r_) * 64 + sc_), \
                                       LDS_AS3(&k_lds[buf_][cb_ * 8]), 16, 0, 0); \
      __builtin_amdgcn_global_load_lds(GBL_AS1(vtbase + (size_t)r_ * 1024 + (kt_) * 64 + sc_), \
                                       LDS_AS3(&vt_lds[buf_][cb_ * 8]), 16, 0, 0); \
    } \
  } while (0)

  // ---- prologue: stage Q [128][64] into k_lds area (scratch), read B-frags ----
  {
    u16* qstage = &k_lds[0][0];
#pragma unroll
    for (int i_ = 0; i_ < 4; ++i_) {
      int cb_ = (wv * 4 + i_) * 64;
      int c_ = cb_ + lane;
      int r_ = c_ >> 3;
      int sc_ = ((c_ & 7) ^ (r_ & 7)) * 8;
      __builtin_amdgcn_global_load_lds(GBL_AS1(qbase + (size_t)r_ * 64 + sc_),
                                       LDS_AS3(qstage + cb_ * 8), 16, 0, 0);
    }
  }
  __syncthreads();
  bf16x8 qf[4];
  {
    int rq = wv * 32 + l31;
    const u16* qr = &k_lds[0][0] + rq * 64;
    int rx = rq & 7;
#pragma unroll
    for (int ds = 0; ds < 4; ++ds)
      qf[ds] = *(const bf16x8*)&qr[((ds * 2 + hi) ^ rx) * 8];
  }
  __syncthreads();
  STAGE_KV(0, 0);
  __syncthreads();

  f32x16 ctx0, ctx1;
#pragma unroll
  for (int z = 0; z < 16; ++z) { ctx0[z] = 0.f; ctx1[z] = 0.f; }
  float psum_half = 0.f;  // this half's running row-sum (disjoint key slots)

  for (int kt = 0; kt < 16; ++kt) {
    const int cur = kt & 1;
    if (kt < 15) STAGE_KV(kt + 1, cur ^ 1);

    // ---- QK^T swapped: D[key][q], lane q = l31, regs = keys (Q pre-scaled) ----
    f32x16 sc[2];
#pragma unroll
    for (int kb = 0; kb < 2; ++kb) {
      f32x16 a;
#pragma unroll
      for (int z = 0; z < 16; ++z) a[z] = 0.f;
      int r = kb * 32 + l31;
      const u16* kr = &k_lds[cur][r * 64];
      int rx = r & 7;
#pragma unroll
      for (int ds = 0; ds < 4; ++ds) {
        bf16x8 kf = *(const bf16x8*)&kr[((ds * 2 + hi) ^ rx) * 8];
        a = __builtin_amdgcn_mfma_f32_32x32x16_bf16(kf, qf[ds], a, 0, 0, 0);
      }
      sc[kb] = a;
    }

    // ---- mask slow path (uniform branch; all-ones input skips entirely) ----
    if (flags[b * 16 + kt]) {
#pragma unroll
      for (int kb = 0; kb < 2; ++kb)
#pragma unroll
        for (int r2 = 0; r2 < 16; ++r2) {
          int key = kb * 32 + (r2 & 3) + 8 * (r2 >> 2) + 4 * hi;
          if (mask[b * 1024 + kt * 64 + key] == 0) sc[kb][r2] = -30000.0f;
        }
    }

    // ---- exp2 (fixed reference) + local row-sum ----
#pragma unroll
    for (int kb = 0; kb < 2; ++kb)
#pragma unroll
      for (int r2 = 0; r2 < 16; ++r2) {
        float p = __builtin_exp2f(sc[kb][r2]);
        sc[kb][r2] = p;
        psum_half += p;
      }

    // ---- P -> bf16 A-frags via cvt_pk + permlane32_swap, then PV ----
#pragma unroll
    for (int kb = 0; kb < 2; ++kb) {
      unsigned int w[8];
#pragma unroll
      for (int j = 0; j < 8; ++j) {
        unsigned int t;
        asm("v_cvt_pk_bf16_f32 %0, %1, %2" : "=v"(t) : "v"(sc[kb][2 * j]), "v"(sc[kb][2 * j + 1]));
        w[j] = t;
      }
      u32x2 a0 = __builtin_amdgcn_permlane32_swap(w[0], w[2], false, false);
      u32x2 a1 = __builtin_amdgcn_permlane32_swap(w[1], w[3], false, false);
      u32x2 a2 = __builtin_amdgcn_permlane32_swap(w[4], w[6], false, false);
      u32x2 a3 = __builtin_amdgcn_permlane32_swap(w[5], w[7], false, false);
      union { u32x4 u; bf16x8 b; } P0, P1;
      P0.u = (u32x4){ a0[0], a1[0], a0[1], a1[1] };
      P1.u = (u32x4){ a2[0], a3[0], a2[1], a3[1] };
#pragma unroll
      for (int db = 0; db < 2; ++db) {
        int rv = db * 32 + l31;
        const u16* vr = &vt_lds[cur][rv * 64];
        int rvx = rv & 7;
        bf16x8 v0 = *(const bf16x8*)&vr[((kb * 4 + hi) ^ rvx) * 8];
        bf16x8 v1 = *(const bf16x8*)&vr[((kb * 4 + 2 + hi) ^ rvx) * 8];
        if (db == 0) {
          ctx0 = __builtin_amdgcn_mfma_f32_32x32x16_bf16(P0.b, v0, ctx0, 0, 0, 0);
          ctx0 = __builtin_amdgcn_mfma_f32_32x32x16_bf16(P1.b, v1, ctx0, 0, 0, 0);
        } else {
          ctx1 = __builtin_amdgcn_mfma_f32_32x32x16_bf16(P0.b, v0, ctx1, 0, 0, 0);
          ctx1 = __builtin_amdgcn_mfma_f32_32x32x16_bf16(P1.b, v1, ctx1, 0, 0, 0);
        }
      }
    }
    __syncthreads();
  }

  // ---- epilogue: combine half-sums, normalize, store ctx [b][s][h*64+d] ----
  float lrow = psum_half + __shfl_xor(psum_half, 32);
  float inv = (lrow > 0.f) ? 1.0f / lrow : 0.f;
  if (hi == 0) scl_lds[wv][l31] = inv;
  asm volatile("s_waitcnt lgkmcnt(0)" ::: "memory");
  const int sbase = qt * 128 + wv * 32;
#pragma unroll
  for (int g = 0; g < 4; ++g) {
    float4 s4 = *(const float4*)&scl_lds[wv][g * 8 + hi * 4];
    const float* sp = (const float*)&s4;
#pragma unroll
    for (int i2 = 0; i2 < 4; ++i2) {
      int s = sbase + g * 8 + hi * 4 + i2;
      size_t rowoff = ((size_t)(b * 1024 + s)) * 1024 + h * 64;
      ctx_ws[rowoff + l31]      = f2bf(ctx0[g * 4 + i2] * sp[i2]);
      ctx_ws[rowoff + 32 + l31] = f2bf(ctx1[g * 4 + i2] * sp[i2]);
    }
  }
#undef STAGE_KV
}

// ---------------- output projection: out = ctx @ Wo^T + bo (fp32 out) ----------------
__global__ __launch_bounds__(256) void out_gemm(const u16* __restrict__ ctxB,
                                                const u16* __restrict__ Wo,
                                                const float* __restrict__ bo,
                                                float* __restrict__ out) {
  __shared__ __align__(16) u16 lds_a[128 * 32];
  __shared__ __align__(16) u16 lds_b[128 * 32];
  const int mt = blockIdx.x, nt = blockIdx.y;
  f32x4 acc[4][4];
#pragma unroll
  for (int i = 0; i < 4; ++i)
#pragma unroll
    for (int j = 0; j < 4; ++j) acc[i][j] = (f32x4){0.f, 0.f, 0.f, 0.f};
  gemm_core(ctxB + (size_t)mt * 128 * 1024, Wo + (size_t)nt * 128 * 1024, lds_a, lds_b, acc);
  const int lane = threadIdx.x & 63, wvi = threadIdx.x >> 6;
  const int wm = wvi >> 1, wn = wvi & 1, fr = lane & 15, fq = lane >> 4;
#pragma unroll
  for (int mi = 0; mi < 4; ++mi)
#pragma unroll
    for (int ni = 0; ni < 4; ++ni)
#pragma unroll
      for (int r = 0; r < 4; ++r) {
        int m = mt * 128 + wm * 64 + mi * 16 + fq * 4 + r;
        int n = nt * 128 + wn * 64 + ni * 16 + fr;
        out[(size_t)m * 1024 + n] = acc[mi][ni][r] + bo[n];
      }
}

extern "C" void kernel_launch(void* const* d_in, const int* in_sizes, int n_in,
                              void* d_out, int out_size, void* d_ws, size_t ws_size,
                              hipStream_t stream) {
  const float* aspect = (const float*)d_in[0];
  const float* opinion = (const float*)d_in[1];
  const int* mask = (const int*)d_in[2];
  const float* Wq = (const float*)d_in[3];
  const float* bq = (const float*)d_in[4];
  const float* Wk = (const float*)d_in[5];
  const float* bk = (const float*)d_in[6];
  const float* Wv = (const float*)d_in[7];
  const float* bv = (const float*)d_in[8];
  const float* Wo = (const float*)d_in[9];
  const float* bo = (const float*)d_in[10];
  // Wbil/bbil unused: span bias is constant along the softmax axis -> cancels.
  float* out = (float*)d_out;
  char* ws = (char*)d_ws;

  const size_t MB = 1u << 20;
  u16* aB    = (u16*)(ws + 0 * MB);
  u16* oB    = (u16*)(ws + 8 * MB);
  u16* WqB   = (u16*)(ws + 16 * MB);
  u16* WkB   = (u16*)(ws + 18 * MB);
  u16* WvB   = (u16*)(ws + 20 * MB);
  u16* WoB   = (u16*)(ws + 22 * MB);
  u16* q_ws  = (u16*)(ws + 24 * MB);  // [b][h][s][d], pre-scaled by 0.125*log2e
  u16* k_ws  = (u16*)(ws + 32 * MB);  // [b][h][s][d]
  u16* vt_ws = (u16*)(ws + 40 * MB);  // [b][h][d][s]
  u16* ctx_ws= (u16*)(ws + 48 * MB);  // [b][s][h*64+d]
  // mask flags in the tail of d_out: written by fused_cast, read by attn,
  // then overwritten by out_gemm (stream-ordered; deterministic every call).
  int* flags = (int*)(out + out_size - 64);

  fused_cast<<<3072, 256, 0, stream>>>(aspect, opinion, Wq, Wk, Wv, Wo, mask,
                                       aB, oB, WqB, WkB, WvB, WoB, flags);
  qkv_gemm<<<dim3(32, 24), 256, 0, stream>>>(aB, oB, WqB, WkB, WvB, bq, bk, bv,
                                             q_ws, k_ws, vt_ws);
  attn_kernel<<<512, 256, 0, stream>>>(q_ws, k_ws, vt_ws, mask, flags, ctx_ws);
  out_gemm<<<dim3(32, 8), 256, 0, stream>>>(ctx_ws, WoB, bo, out);
}

// Round 20
// 108.698 us; speedup vs baseline: 1.1714x; 1.0068x over previous
//
#include <hip/hip_runtime.h>
#include <hip/hip_bf16.h>
#include <stdint.h>

typedef __attribute__((ext_vector_type(4))) float f32x4;
typedef __attribute__((ext_vector_type(16))) float f32x16;
typedef __attribute__((ext_vector_type(8))) short bf16x8;
typedef __attribute__((ext_vector_type(4))) unsigned int u32x4;
typedef __attribute__((ext_vector_type(2))) unsigned int u32x2;
typedef unsigned short u16;

#define GBL_AS1(p) ((const __attribute__((address_space(1))) void*)(p))
#define LDS_AS3(p) ((__attribute__((address_space(3))) void*)(p))

static __device__ __forceinline__ u16 f2bf(float f) {
  __hip_bfloat16 h = __float2bfloat16(f);
  union { __hip_bfloat16 h; u16 u; } c; c.h = h;
  return c.u;
}

// ---------------- weights fp32->bf16 cast + mask flags (24MB traffic, ~4us) ----------------
// aspect/opinion are no longer pre-cast: qkv stages them fp32->bf16 in-register.
__global__ __launch_bounds__(256) void cast_weights(
    const float* __restrict__ wq_, const float* __restrict__ wk_,
    const float* __restrict__ wv_, const float* __restrict__ wo_,
    const int* __restrict__ mask,
    u16* __restrict__ WqB, u16* __restrict__ WkB,
    u16* __restrict__ WvB, u16* __restrict__ WoB,
    int* __restrict__ flags) {
  if (blockIdx.x == 0 && threadIdx.x < 64) {
    int bb = threadIdx.x >> 4, kt = threadIdx.x & 15;
    int anyz = 0;
    for (int s = 0; s < 64; ++s) anyz |= (mask[bb * 1024 + kt * 64 + s] == 0);
    flags[threadIdx.x] = anyz;
  }
  int idx = blockIdx.x * 256 + threadIdx.x;  // grid 1024: idx in [0, 262144)
#pragma unroll
  for (int j = 0; j < 4; ++j) {
    int i = idx + j * 262144;
    int w = i >> 18, off = i & 262143;
    const float* src = (w == 0) ? wq_ : (w == 1) ? wk_ : (w == 2) ? wv_ : wo_;
    u16* dst = (w == 0) ? WqB : (w == 1) ? WkB : (w == 2) ? WvB : WoB;
    float4 v = reinterpret_cast<const float4*>(src)[off];
    ushort4 ov;
    ov.x = f2bf(v.x); ov.y = f2bf(v.y); ov.z = f2bf(v.z); ov.w = f2bf(v.w);
    reinterpret_cast<ushort4*>(dst)[off] = ov;
  }
}

// ---------------- 128x128 NT-GEMM core (m97 structure): BK=32, single buffer ----------------
// Empirical optimum for this K=1024 shape (kept for out_gemm). Do not perturb.
static __device__ __forceinline__ void gemm_core(const u16* __restrict__ Atile,
                                                 const u16* __restrict__ Btile,
                                                 u16* lds_a, u16* lds_b,
                                                 f32x4 acc[4][4]) {
  const int tid = threadIdx.x;
  const int lane = tid & 63;
  const int wv = tid >> 6;
  const int wm = wv >> 1, wn = wv & 1;
  const int fr = lane & 15, fq = lane >> 4;
  for (int kt = 0; kt < 32; ++kt) {
#pragma unroll
    for (int i = 0; i < 2; ++i) {
      const int cb = (wv * 2 + i) * 64;
      const int c = cb + lane;
      const int row = c >> 2;
      const int off = (c & 3) * 8;
      __builtin_amdgcn_global_load_lds(GBL_AS1(Atile + (size_t)row * 1024 + kt * 32 + off),
                                       LDS_AS3(lds_a + cb * 8), 16, 0, 0);
      __builtin_amdgcn_global_load_lds(GBL_AS1(Btile + (size_t)row * 1024 + kt * 32 + off),
                                       LDS_AS3(lds_b + cb * 8), 16, 0, 0);
    }
    __syncthreads();
    bf16x8 af[4], bfv[4];
#pragma unroll
    for (int mi = 0; mi < 4; ++mi)
      af[mi] = *(const bf16x8*)&lds_a[(wm * 64 + mi * 16 + fr) * 32 + fq * 8];
#pragma unroll
    for (int ni = 0; ni < 4; ++ni)
      bfv[ni] = *(const bf16x8*)&lds_b[(wn * 64 + ni * 16 + fr) * 32 + fq * 8];
#pragma unroll
    for (int mi = 0; mi < 4; ++mi)
#pragma unroll
      for (int ni = 0; ni < 4; ++ni)
        acc[mi][ni] = __builtin_amdgcn_mfma_f32_16x16x32_bf16(af[mi], bfv[ni], acc[mi][ni], 0, 0, 0);
    __syncthreads();
  }
}

// ---------------- gemm core with fp32 A source (cast fused into staging) ----------------
// A-tile staged via regs: 4x global_load_dwordx4 (f32) -> 8x v_cvt_pk_bf16_f32
// -> 2x ds_write_b128, producing a byte-identical LDS layout. Inner MFMA loop,
// fragment reads, B gload_lds path, and barriers are unchanged from gemm_core.
static __device__ __forceinline__ void gemm_core_f32a(const float* __restrict__ A32,
                                                      const u16* __restrict__ Btile,
                                                      u16* lds_a, u16* lds_b,
                                                      f32x4 acc[4][4]) {
  const int tid = threadIdx.x;
  const int lane = tid & 63;
  const int wv = tid >> 6;
  const int wm = wv >> 1, wn = wv & 1;
  const int fr = lane & 15, fq = lane >> 4;
  for (int kt = 0; kt < 32; ++kt) {
    // A: fp32 loads issued first (latency overlaps B staging + cvt)
    float4 a0[2], a1[2];
#pragma unroll
    for (int i = 0; i < 2; ++i) {
      const int c = (wv * 2 + i) * 64 + lane;
      const int row = c >> 2;
      const int off = (c & 3) * 8;
      const float* s = A32 + (size_t)row * 1024 + kt * 32 + off;
      a0[i] = *(const float4*)s;
      a1[i] = *(const float4*)(s + 4);
    }
    // B: bf16 weights via global_load_lds (unchanged)
#pragma unroll
    for (int i = 0; i < 2; ++i) {
      const int cb = (wv * 2 + i) * 64;
      const int c = cb + lane;
      const int row = c >> 2;
      const int off = (c & 3) * 8;
      __builtin_amdgcn_global_load_lds(GBL_AS1(Btile + (size_t)row * 1024 + kt * 32 + off),
                                       LDS_AS3(lds_b + cb * 8), 16, 0, 0);
    }
    // cvt + ds_write A (same chunk layout as the bf16 path)
#pragma unroll
    for (int i = 0; i < 2; ++i) {
      const int c = (wv * 2 + i) * 64 + lane;
      unsigned int w0, w1, w2, w3;
      asm("v_cvt_pk_bf16_f32 %0, %1, %2" : "=v"(w0) : "v"(a0[i].x), "v"(a0[i].y));
      asm("v_cvt_pk_bf16_f32 %0, %1, %2" : "=v"(w1) : "v"(a0[i].z), "v"(a0[i].w));
      asm("v_cvt_pk_bf16_f32 %0, %1, %2" : "=v"(w2) : "v"(a1[i].x), "v"(a1[i].y));
      asm("v_cvt_pk_bf16_f32 %0, %1, %2" : "=v"(w3) : "v"(a1[i].z), "v"(a1[i].w));
      *(u32x4*)&lds_a[c * 8] = (u32x4){w0, w1, w2, w3};
    }
    __syncthreads();
    bf16x8 af[4], bfv[4];
#pragma unroll
    for (int mi = 0; mi < 4; ++mi)
      af[mi] = *(const bf16x8*)&lds_a[(wm * 64 + mi * 16 + fr) * 32 + fq * 8];
#pragma unroll
    for (int ni = 0; ni < 4; ++ni)
      bfv[ni] = *(const bf16x8*)&lds_b[(wn * 64 + ni * 16 + fr) * 32 + fq * 8];
#pragma unroll
    for (int mi = 0; mi < 4; ++mi)
#pragma unroll
      for (int ni = 0; ni < 4; ++ni)
        acc[mi][ni] = __builtin_amdgcn_mfma_f32_16x16x32_bf16(af[mi], bfv[ni], acc[mi][ni], 0, 0, 0);
    __syncthreads();
  }
}

// ---------------- fused QKV projection (A read fp32 directly; cast fused) ----------------
__global__ __launch_bounds__(256) void qkv_gemm(
    const float* __restrict__ aspect32, const float* __restrict__ opinion32,
    const u16* __restrict__ Wq, const u16* __restrict__ Wk, const u16* __restrict__ Wv,
    const float* __restrict__ bq, const float* __restrict__ bk, const float* __restrict__ bv,
    u16* __restrict__ q_ws, u16* __restrict__ k_ws, u16* __restrict__ vt_ws) {
  __shared__ __align__(16) u16 lds_a[128 * 32];
  __shared__ __align__(16) u16 lds_b[128 * 32];
  const int mt = blockIdx.x;
  const int nt = blockIdx.y;
  const int w = nt >> 3, ntl = nt & 7;
  const float* A32 = (w == 0) ? aspect32 : opinion32;
  const u16* W = (w == 0) ? Wq : (w == 1) ? Wk : Wv;
  const float* bias = (w == 0) ? bq : (w == 1) ? bk : bv;
  f32x4 acc[4][4];
#pragma unroll
  for (int i = 0; i < 4; ++i)
#pragma unroll
    for (int j = 0; j < 4; ++j) acc[i][j] = (f32x4){0.f, 0.f, 0.f, 0.f};
  gemm_core_f32a(A32 + (size_t)mt * 128 * 1024, W + (size_t)ntl * 128 * 1024,
                 lds_a, lds_b, acc);
  const int lane = threadIdx.x & 63, wvi = threadIdx.x >> 6;
  const int wm = wvi >> 1, wn = wvi & 1, fr = lane & 15, fq = lane >> 4;
  u16* dst01 = (w == 0) ? q_ws : k_ws;
  const float qscl = (w == 0) ? 0.18033688f : 1.0f;  // 0.125 * log2(e) folded into Q
#pragma unroll
  for (int mi = 0; mi < 4; ++mi)
#pragma unroll
    for (int ni = 0; ni < 4; ++ni)
#pragma unroll
      for (int r = 0; r < 4; ++r) {
        int m = mt * 128 + wm * 64 + mi * 16 + fq * 4 + r;
        int nl = ntl * 128 + wn * 64 + ni * 16 + fr;
        float v = (acc[mi][ni][r] + bias[nl]) * qscl;
        int b = m >> 10, s = m & 1023, h = nl >> 6, d = nl & 63;
        u16 u = f2bf(v);
        if (w < 2) dst01[(((size_t)(b * 16 + h)) * 1024 + s) * 64 + d] = u;
        else       vt_ws[(((size_t)(b * 16 + h)) * 64 + d) * 1024 + s] = u;
      }
}

// ---------------- flash attention, swapped-QK^T 32x32, KVBLK=64 (r16 structure) ----------------
__global__ __launch_bounds__(256, 4) void attn_kernel(
    const u16* __restrict__ q_ws, const u16* __restrict__ k_ws,
    const u16* __restrict__ vt_ws, const int* __restrict__ mask,
    const int* __restrict__ flags, u16* __restrict__ ctx_ws) {
  __shared__ __align__(16) u16 k_lds[2][64 * 64];   // K [64 keys][64 d], chunk-swizzled
  __shared__ __align__(16) u16 vt_lds[2][64 * 64];  // V^T [64 d][64 keys], chunk-swizzled
  __shared__ __align__(16) float scl_lds[4][32];
  const int bid = blockIdx.x;
  const int bh = bid & 63, qt = bid >> 6;
  const int b = bh >> 4, h = bh & 15;
  const int tid = threadIdx.x, lane = tid & 63, wv = tid >> 6;
  const int l31 = lane & 31, hi = lane >> 5;
  const u16* qbase = q_ws + (size_t)bh * 65536 + (size_t)qt * 8192;
  const u16* kbase = k_ws + (size_t)bh * 65536;
  const u16* vtbase = vt_ws + (size_t)bh * 65536;

#define STAGE_KV(kt_, buf_) do { \
    _Pragma("unroll") \
    for (int i_ = 0; i_ < 2; ++i_) { \
      int cb_ = (wv * 2 + i_) * 64; \
      int c_ = cb_ + lane; \
      int r_ = c_ >> 3; \
      int sc_ = ((c_ & 7) ^ (r_ & 7)) * 8; \
      __builtin_amdgcn_global_load_lds(GBL_AS1(kbase + (size_t)((kt_) * 64 + r_) * 64 + sc_), \
                                       LDS_AS3(&k_lds[buf_][cb_ * 8]), 16, 0, 0); \
      __builtin_amdgcn_global_load_lds(GBL_AS1(vtbase + (size_t)r_ * 1024 + (kt_) * 64 + sc_), \
                                       LDS_AS3(&vt_lds[buf_][cb_ * 8]), 16, 0, 0); \
    } \
  } while (0)

  // ---- prologue: stage Q [128][64] into k_lds area (scratch), read B-frags ----
  {
    u16* qstage = &k_lds[0][0];
#pragma unroll
    for (int i_ = 0; i_ < 4; ++i_) {
      int cb_ = (wv * 4 + i_) * 64;
      int c_ = cb_ + lane;
      int r_ = c_ >> 3;
      int sc_ = ((c_ & 7) ^ (r_ & 7)) * 8;
      __builtin_amdgcn_global_load_lds(GBL_AS1(qbase + (size_t)r_ * 64 + sc_),
                                       LDS_AS3(qstage + cb_ * 8), 16, 0, 0);
    }
  }
  __syncthreads();
  bf16x8 qf[4];
  {
    int rq = wv * 32 + l31;
    const u16* qr = &k_lds[0][0] + rq * 64;
    int rx = rq & 7;
#pragma unroll
    for (int ds = 0; ds < 4; ++ds)
      qf[ds] = *(const bf16x8*)&qr[((ds * 2 + hi) ^ rx) * 8];
  }
  __syncthreads();
  STAGE_KV(0, 0);
  __syncthreads();

  f32x16 ctx0, ctx1;
#pragma unroll
  for (int z = 0; z < 16; ++z) { ctx0[z] = 0.f; ctx1[z] = 0.f; }
  float psum_half = 0.f;  // this half's running row-sum (disjoint key slots)

  for (int kt = 0; kt < 16; ++kt) {
    const int cur = kt & 1;
    if (kt < 15) STAGE_KV(kt + 1, cur ^ 1);

    // ---- QK^T swapped: D[key][q], lane q = l31, regs = keys (Q pre-scaled) ----
    f32x16 sc[2];
#pragma unroll
    for (int kb = 0; kb < 2; ++kb) {
      f32x16 a;
#pragma unroll
      for (int z = 0; z < 16; ++z) a[z] = 0.f;
      int r = kb * 32 + l31;
      const u16* kr = &k_lds[cur][r * 64];
      int rx = r & 7;
#pragma unroll
      for (int ds = 0; ds < 4; ++ds) {
        bf16x8 kf = *(const bf16x8*)&kr[((ds * 2 + hi) ^ rx) * 8];
        a = __builtin_amdgcn_mfma_f32_32x32x16_bf16(kf, qf[ds], a, 0, 0, 0);
      }
      sc[kb] = a;
    }

    // ---- mask slow path (uniform branch; all-ones input skips entirely) ----
    if (flags[b * 16 + kt]) {
#pragma unroll
      for (int kb = 0; kb < 2; ++kb)
#pragma unroll
        for (int r2 = 0; r2 < 16; ++r2) {
          int key = kb * 32 + (r2 & 3) + 8 * (r2 >> 2) + 4 * hi;
          if (mask[b * 1024 + kt * 64 + key] == 0) sc[kb][r2] = -30000.0f;
        }
    }

    // ---- exp2 (fixed reference) + local row-sum ----
#pragma unroll
    for (int kb = 0; kb < 2; ++kb)
#pragma unroll
      for (int r2 = 0; r2 < 16; ++r2) {
        float p = __builtin_exp2f(sc[kb][r2]);
        sc[kb][r2] = p;
        psum_half += p;
      }

    // ---- P -> bf16 A-frags via cvt_pk + permlane32_swap, then PV ----
#pragma unroll
    for (int kb = 0; kb < 2; ++kb) {
      unsigned int w[8];
#pragma unroll
      for (int j = 0; j < 8; ++j) {
        unsigned int t;
        asm("v_cvt_pk_bf16_f32 %0, %1, %2" : "=v"(t) : "v"(sc[kb][2 * j]), "v"(sc[kb][2 * j + 1]));
        w[j] = t;
      }
      u32x2 a0 = __builtin_amdgcn_permlane32_swap(w[0], w[2], false, false);
      u32x2 a1 = __builtin_amdgcn_permlane32_swap(w[1], w[3], false, false);
      u32x2 a2 = __builtin_amdgcn_permlane32_swap(w[4], w[6], false, false);
      u32x2 a3 = __builtin_amdgcn_permlane32_swap(w[5], w[7], false, false);
      union { u32x4 u; bf16x8 b; } P0, P1;
      P0.u = (u32x4){ a0[0], a1[0], a0[1], a1[1] };
      P1.u = (u32x4){ a2[0], a3[0], a2[1], a3[1] };
#pragma unroll
      for (int db = 0; db < 2; ++db) {
        int rv = db * 32 + l31;
        const u16* vr = &vt_lds[cur][rv * 64];
        int rvx = rv & 7;
        bf16x8 v0 = *(const bf16x8*)&vr[((kb * 4 + hi) ^ rvx) * 8];
        bf16x8 v1 = *(const bf16x8*)&vr[((kb * 4 + 2 + hi) ^ rvx) * 8];
        if (db == 0) {
          ctx0 = __builtin_amdgcn_mfma_f32_32x32x16_bf16(P0.b, v0, ctx0, 0, 0, 0);
          ctx0 = __builtin_amdgcn_mfma_f32_32x32x16_bf16(P1.b, v1, ctx0, 0, 0, 0);
        } else {
          ctx1 = __builtin_amdgcn_mfma_f32_32x32x16_bf16(P0.b, v0, ctx1, 0, 0, 0);
          ctx1 = __builtin_amdgcn_mfma_f32_32x32x16_bf16(P1.b, v1, ctx1, 0, 0, 0);
        }
      }
    }
    __syncthreads();
  }

  // ---- epilogue: combine half-sums, normalize, store ctx [b][s][h*64+d] ----
  float lrow = psum_half + __shfl_xor(psum_half, 32);
  float inv = (lrow > 0.f) ? 1.0f / lrow : 0.f;
  if (hi == 0) scl_lds[wv][l31] = inv;
  asm volatile("s_waitcnt lgkmcnt(0)" ::: "memory");
  const int sbase = qt * 128 + wv * 32;
#pragma unroll
  for (int g = 0; g < 4; ++g) {
    float4 s4 = *(const float4*)&scl_lds[wv][g * 8 + hi * 4];
    const float* sp = (const float*)&s4;
#pragma unroll
    for (int i2 = 0; i2 < 4; ++i2) {
      int s = sbase + g * 8 + hi * 4 + i2;
      size_t rowoff = ((size_t)(b * 1024 + s)) * 1024 + h * 64;
      ctx_ws[rowoff + l31]      = f2bf(ctx0[g * 4 + i2] * sp[i2]);
      ctx_ws[rowoff + 32 + l31] = f2bf(ctx1[g * 4 + i2] * sp[i2]);
    }
  }
#undef STAGE_KV
}

// ---------------- output projection: out = ctx @ Wo^T + bo (r16 structure) ----------------
__global__ __launch_bounds__(256) void out_gemm(const u16* __restrict__ ctxB,
                                                const u16* __restrict__ Wo,
                                                const float* __restrict__ bo,
                                                float* __restrict__ out) {
  __shared__ __align__(16) u16 lds_a[128 * 32];
  __shared__ __align__(16) u16 lds_b[128 * 32];
  const int mt = blockIdx.x, nt = blockIdx.y;
  f32x4 acc[4][4];
#pragma unroll
  for (int i = 0; i < 4; ++i)
#pragma unroll
    for (int j = 0; j < 4; ++j) acc[i][j] = (f32x4){0.f, 0.f, 0.f, 0.f};
  gemm_core(ctxB + (size_t)mt * 128 * 1024, Wo + (size_t)nt * 128 * 1024, lds_a, lds_b, acc);
  const int lane = threadIdx.x & 63, wvi = threadIdx.x >> 6;
  const int wm = wvi >> 1, wn = wvi & 1, fr = lane & 15, fq = lane >> 4;
#pragma unroll
  for (int mi = 0; mi < 4; ++mi)
#pragma unroll
    for (int ni = 0; ni < 4; ++ni)
#pragma unroll
      for (int r = 0; r < 4; ++r) {
        int m = mt * 128 + wm * 64 + mi * 16 + fq * 4 + r;
        int n = nt * 128 + wn * 64 + ni * 16 + fr;
        out[(size_t)m * 1024 + n] = acc[mi][ni][r] + bo[n];
      }
}

extern "C" void kernel_launch(void* const* d_in, const int* in_sizes, int n_in,
                              void* d_out, int out_size, void* d_ws, size_t ws_size,
                              hipStream_t stream) {
  const float* aspect = (const float*)d_in[0];
  const float* opinion = (const float*)d_in[1];
  const int* mask = (const int*)d_in[2];
  const float* Wq = (const float*)d_in[3];
  const float* bq = (const float*)d_in[4];
  const float* Wk = (const float*)d_in[5];
  const float* bk = (const float*)d_in[6];
  const float* Wv = (const float*)d_in[7];
  const float* bv = (const float*)d_in[8];
  const float* Wo = (const float*)d_in[9];
  const float* bo = (const float*)d_in[10];
  // Wbil/bbil unused: span bias is constant along the softmax axis -> cancels.
  float* out = (float*)d_out;
  char* ws = (char*)d_ws;

  const size_t MB = 1u << 20;
  u16* WqB   = (u16*)(ws + 16 * MB);
  u16* WkB   = (u16*)(ws + 18 * MB);
  u16* WvB   = (u16*)(ws + 20 * MB);
  u16* WoB   = (u16*)(ws + 22 * MB);
  u16* q_ws  = (u16*)(ws + 24 * MB);  // [b][h][s][d], pre-scaled by 0.125*log2e
  u16* k_ws  = (u16*)(ws + 32 * MB);  // [b][h][s][d]
  u16* vt_ws = (u16*)(ws + 40 * MB);  // [b][h][d][s]
  u16* ctx_ws= (u16*)(ws + 48 * MB);  // [b][s][h*64+d]
  // mask flags in the tail of d_out: written by cast_weights, read by attn,
  // then overwritten by out_gemm (stream-ordered; deterministic every call).
  int* flags = (int*)(out + out_size - 64);

  cast_weights<<<1024, 256, 0, stream>>>(Wq, Wk, Wv, Wo, mask,
                                         WqB, WkB, WvB, WoB, flags);
  qkv_gemm<<<dim3(32, 24), 256, 0, stream>>>(aspect, opinion, WqB, WkB, WvB,
                                             bq, bk, bv, q_ws, k_ws, vt_ws);
  attn_kernel<<<512, 256, 0, stream>>>(q_ws, k_ws, vt_ws, mask, flags, ctx_ws);
  out_gemm<<<dim3(32, 8), 256, 0, stream>>>(ctx_ws, WoB, bo, out);
}